// Round 11
// baseline (300.323 us; speedup 1.0000x reference)
//
#include <hip/hip_runtime.h>
#include <hip/hip_bf16.h>
#include <math.h>
#include <stdint.h>

// ScaleAdaptiveRouter on MI355X (gfx950) — Round 11: barrier-free K-loop,
// named-register pipelines (B 2-deep from L2, A 4-deep from HBM).
// T=16384, H=2048, E=64, K=2112, top-2.
//
// R10 post-mortem: __syncthreads emits s_waitcnt vmcnt(0) -> drains the
// just-issued prefetches every step; prefetch distance is irrelevant with a
// barrier in the loop (R6/R9/R10 all ~95us). R8 was barrier-free but its
// 96-VGPR prefetch array spilled. R11: barrier-free + pipelines that fit:
//   * wave = (m-tile, 32-expert group) -> 6 B-records/step (24+24 VGPR, 2-deep)
//   * A 4-deep named float4 pairs (32 VGPR) -> ~1000cyc cover > HBM latency
//   * B-frags read directly from Wp: per-lane coalesced 16B, L2-resident
//   * no K-loop LDS/barriers at all; grid 512 -> 8 waves/CU
// bf16x3 6-term product (verified R6-R10): error ~2^-24/elt.

#define H_DIM 2048
#define K_TOTAL 2112
#define E_DIM 64
#define SE_DIM 64
#define NSTEP 64                        // K32 steps over H
#define TPB 32                          // tokens per block
#define NBLOCKS (16384 / TPB)           // 512
#define STEP_BYTES (12 * 1024)          // 12 B-records of 1 KB per step
#define WP_TOTAL (NSTEP * STEP_BYTES)   // 786432 B
#define MINS(v) ((v) < NSTEP ? (v) : (NSTEP - 1))

typedef float  f32x4 __attribute__((ext_vector_type(4)));
typedef short  s16x8 __attribute__((ext_vector_type(8)));
typedef unsigned int u32x4 __attribute__((ext_vector_type(4)));

__device__ __forceinline__ unsigned short bf16_rne(float f) {
    uint32_t u = __float_as_uint(f);
    return (unsigned short)((u + 0x7FFFu + ((u >> 16) & 1u)) >> 16);
}
__device__ __forceinline__ float bf16_f32(unsigned short h) {
    return __uint_as_float(((uint32_t)h) << 16);
}
__device__ __forceinline__ uint32_t bits_of_bf2(__hip_bfloat162 h) {
    uint32_t u; __builtin_memcpy(&u, &h, 4); return u;
}

// ---- prep: split W into 3 bf16 planes laid out as MFMA B-fragments ----
// B-frag (16x16x32): lane l -> n = l&15, k = (l>>4)*8 + j. Record (s,nt,p):
// 64 lanes x 8 bf16 = 1 KB; record index = s*12 + nt*3 + p.  [R6-verified]
__global__ void prep_kernel(const float* __restrict__ W,
                            const float* __restrict__ se,
                            const int* __restrict__ sidx,
                            unsigned short* __restrict__ Wp,
                            float* __restrict__ tail) {
    if (blockIdx.x == 64) {
        int e = threadIdx.x;
        if (e < 64) {
            const float* emb = se + (*sidx) * SE_DIM;
            float t = 0.f;
            for (int j = 0; j < SE_DIM; ++j)
                t = fmaf(emb[j], W[(size_t)e * K_TOTAL + H_DIM + j], t);
            tail[e] = t;
        }
        return;
    }
    int item = blockIdx.x * 256 + threadIdx.x;   // (s, nt, lane)
    int lane = item & 63;
    int nt   = (item >> 6) & 3;
    int s    = item >> 8;
    int e     = nt * 16 + (lane & 15);
    int kbase = s * 32 + (lane >> 4) * 8;
    const float* wr = W + (size_t)e * K_TOTAL + kbase;
    unsigned short p0[8], p1[8], p2[8];
    #pragma unroll
    for (int j = 0; j < 8; ++j) {
        float v = wr[j];
        unsigned short a0 = bf16_rne(v);
        float r1 = v - bf16_f32(a0);
        unsigned short a1 = bf16_rne(r1);
        float r2 = r1 - bf16_f32(a1);
        p0[j] = a0; p1[j] = a1; p2[j] = bf16_rne(r2);
    }
    size_t rec = (size_t)s * 12 + nt * 3;
    unsigned short* d0 = Wp + (rec + 0) * 512 + lane * 8;
    unsigned short* d1 = Wp + (rec + 1) * 512 + lane * 8;
    unsigned short* d2 = Wp + (rec + 2) * 512 + lane * 8;
    #pragma unroll
    for (int j = 0; j < 8; ++j) { d0[j] = p0[j]; d1[j] = p1[j]; d2[j] = p2[j]; }
}

// split 8 consecutive-k floats into 3 bf16 A-fragment planes (packed pairs)
__device__ __forceinline__ void split3(const float4 fa, const float4 fb,
                                       s16x8& P0, s16x8& P1, s16x8& P2) {
    float f[8] = {fa.x, fa.y, fa.z, fa.w, fb.x, fb.y, fb.z, fb.w};
    uint32_t d0[4], d1[4], d2[4];
    #pragma unroll
    for (int p = 0; p < 4; ++p) {
        float v0 = f[2 * p], v1 = f[2 * p + 1];
        uint32_t u0 = bits_of_bf2(__float22bfloat162_rn(make_float2(v0, v1)));
        float r0 = v0 - __uint_as_float(u0 << 16);
        float r1 = v1 - __uint_as_float(u0 & 0xffff0000u);
        uint32_t u1 = bits_of_bf2(__float22bfloat162_rn(make_float2(r0, r1)));
        float s0 = r0 - __uint_as_float(u1 << 16);
        float s1 = r1 - __uint_as_float(u1 & 0xffff0000u);
        uint32_t u2 = bits_of_bf2(__float22bfloat162_rn(make_float2(s0, s1)));
        d0[p] = u0; d1[p] = u1; d2[p] = u2;
    }
    u32x4 q0 = {d0[0], d0[1], d0[2], d0[3]};
    u32x4 q1 = {d1[0], d1[1], d1[2], d1[3]};
    u32x4 q2 = {d2[0], d2[1], d2[2], d2[3]};
    __builtin_memcpy(&P0, &q0, 16);
    __builtin_memcpy(&P1, &q1, 16);
    __builtin_memcpy(&P2, &q2, 16);
}

// load this wave's 6 B-records for step sidx into named uint4s
#define LDB(r0, r1, r2, r3, r4, r5, sidx) do {                          \
    const char* _p = bptr + (size_t)(sidx) * STEP_BYTES;                \
    r0 = *(const uint4*)(_p);                                           \
    r1 = *(const uint4*)(_p + 1024);                                    \
    r2 = *(const uint4*)(_p + 2048);                                    \
    r3 = *(const uint4*)(_p + 3072);                                    \
    r4 = *(const uint4*)(_p + 4096);                                    \
    r5 = *(const uint4*)(_p + 5120);                                    \
} while (0)

// load this lane's A pair for step sidx
#define LDA(da, db, sidx) do {                                          \
    const float* _a = aptr + (size_t)(sidx) * 32;                       \
    da = *(const float4*)(_a);                                          \
    db = *(const float4*)(_a + 4);                                      \
} while (0)

#define MFMA6(A0, A1, A2, b0, b1, b2, accv) do {                              \
    accv = __builtin_amdgcn_mfma_f32_16x16x32_bf16(A0, b0, accv, 0, 0, 0);    \
    accv = __builtin_amdgcn_mfma_f32_16x16x32_bf16(A0, b1, accv, 0, 0, 0);    \
    accv = __builtin_amdgcn_mfma_f32_16x16x32_bf16(A1, b0, accv, 0, 0, 0);    \
    accv = __builtin_amdgcn_mfma_f32_16x16x32_bf16(A0, b2, accv, 0, 0, 0);    \
    accv = __builtin_amdgcn_mfma_f32_16x16x32_bf16(A1, b1, accv, 0, 0, 0);    \
    accv = __builtin_amdgcn_mfma_f32_16x16x32_bf16(A2, b0, accv, 0, 0, 0);    \
} while (0)

#define COMPUTE(Aa, Ab, r0, r1, r2, r3, r4, r5) do {                    \
    s16x8 A0, A1, A2; split3(Aa, Ab, A0, A1, A2);                       \
    s16x8 b0, b1, b2, b3, b4, b5;                                       \
    __builtin_memcpy(&b0, &r0, 16); __builtin_memcpy(&b1, &r1, 16);     \
    __builtin_memcpy(&b2, &r2, 16); __builtin_memcpy(&b3, &r3, 16);     \
    __builtin_memcpy(&b4, &r4, 16); __builtin_memcpy(&b5, &r5, 16);     \
    MFMA6(A0, A1, A2, b0, b1, b2, acc0);                                \
    MFMA6(A0, A1, A2, b3, b4, b5, acc1);                                \
} while (0)

__launch_bounds__(256, 2)
__global__ void router_kernel(const float* __restrict__ x,
                              const unsigned char* __restrict__ Wp,
                              const float* __restrict__ tail_g,
                              const float* __restrict__ noise,
                              float* __restrict__ out) {
    __shared__ float4 cand2[2][TPB];                            // 1 KB
    __shared__ float4 res[TPB];                                 // 0.5 KB

    const int tid  = threadIdx.x;
    const int lane = tid & 63;
    const int wave = __builtin_amdgcn_readfirstlane(tid >> 6);
    const int mt   = wave >> 1;         // m-tile 0/1 (16 tokens each)
    const int g    = wave & 1;          // expert group: experts g*32 .. g*32+31
    const int tok0 = blockIdx.x * TPB;
    const int row  = lane & 15;         // token within m-tile
    const int quad = lane >> 4;         // k-quad
    const int c    = row;               // expert col within 16-slice

    // A source: this lane's token row, k = s*32 + quad*8 + (0..7)
    const float* aptr = x + (size_t)(tok0 + mt * 16 + row) * H_DIM + quad * 8;
    // B source: this wave's 6 records per step, per-lane coalesced 16B
    const char* bptr = (const char*)Wp + g * 6144 + lane * 16;

    f32x4 acc0 = {0.f, 0.f, 0.f, 0.f}, acc1 = acc0;

    // ---- prologue: fill A 4-deep, B 2-deep ----
    float4 A0a, A0b, A1a, A1b, A2a, A2b, A3a, A3b;
    uint4 c0, c1, c2, c3, c4, c5;       // B slot for even steps
    uint4 n0, n1, n2, n3, n4, n5;       // B slot for odd steps
    LDA(A0a, A0b, 0); LDA(A1a, A1b, 1); LDA(A2a, A2b, 2); LDA(A3a, A3b, 3);
    LDB(c0, c1, c2, c3, c4, c5, 0);
    LDB(n0, n1, n2, n3, n4, n5, 1);

    // ---- barrier-free K loop: 4-phase rotation, fine-grained vmcnt only ----
    for (int sb = 0; sb < NSTEP; sb += 4) {
        // phase 0: s = sb
        COMPUTE(A0a, A0b, c0, c1, c2, c3, c4, c5);
        LDA(A0a, A0b, MINS(sb + 4));
        LDB(c0, c1, c2, c3, c4, c5, MINS(sb + 2));
        // phase 1: s = sb+1
        COMPUTE(A1a, A1b, n0, n1, n2, n3, n4, n5);
        LDA(A1a, A1b, MINS(sb + 5));
        LDB(n0, n1, n2, n3, n4, n5, MINS(sb + 3));
        // phase 2: s = sb+2
        COMPUTE(A2a, A2b, c0, c1, c2, c3, c4, c5);
        LDA(A2a, A2b, MINS(sb + 6));
        LDB(c0, c1, c2, c3, c4, c5, MINS(sb + 4));
        // phase 3: s = sb+3
        COMPUTE(A3a, A3b, n0, n1, n2, n3, n4, n5);
        LDA(A3a, A3b, MINS(sb + 7));
        LDB(n0, n1, n2, n3, n4, n5, MINS(sb + 5));
    }

    // ---- epilogue: tail + noise, top-2 over this wave's 32 experts ----
    // C/D: col = lane&15 -> expert g*32 + nt*16 + c; row = quad*4 + r -> token
    float tl0 = tail_g[g * 32 + c], tl1 = tail_g[g * 32 + 16 + c];
    #pragma unroll
    for (int r = 0; r < 4; ++r) {
        const int tl = mt * 16 + quad * 4 + r;              // block-local token
        const float* nz = noise + (size_t)(tok0 + tl) * E_DIM + g * 32;
        float v0 = acc0[r] + tl0 + 0.1f * nz[c];
        float v1 = acc1[r] + tl1 + 0.1f * nz[16 + c];
        // per-lane top-2 (v0's index < v1's index -> ties keep v0)
        float V1, V2; int I1, I2;
        if (v1 > v0) { V1 = v1; I1 = g * 32 + 16 + c; V2 = v0; I2 = g * 32 + c; }
        else         { V1 = v0; I1 = g * 32 + c;      V2 = v1; I2 = g * 32 + 16 + c; }
        // butterfly over the 16 lanes of this quad group
        #pragma unroll
        for (int m = 8; m; m >>= 1) {
            float o1 = __shfl_xor(V1, m, 64); int oi1 = __shfl_xor(I1, m, 64);
            float o2 = __shfl_xor(V2, m, 64); int oi2 = __shfl_xor(I2, m, 64);
            if (o1 > V1 || (o1 == V1 && oi1 < I1)) {
                float nv2; int ni2;
                if (V1 > o2 || (V1 == o2 && I1 < oi2)) { nv2 = V1; ni2 = I1; }
                else                                   { nv2 = o2; ni2 = oi2; }
                V1 = o1; I1 = oi1; V2 = nv2; I2 = ni2;
            } else {
                if (o1 > V2 || (o1 == V2 && oi1 < I2)) { V2 = o1; I2 = oi1; }
            }
        }
        if (c == r)
            cand2[g][tl] = make_float4(V1, __int_as_float(I1), V2, __int_as_float(I2));
    }
    __syncthreads();

    // ---- merge the two 32-expert groups per token (disjoint ranges: ties exact) ----
    if (tid < TPB) {
        float4 q0 = cand2[0][tid];                  // experts 0..31 (lower idx)
        float4 q1 = cand2[1][tid];                  // experts 32..63
        float V1 = q0.x, V2 = q0.z;
        int   I1 = __float_as_int(q0.y), I2 = __float_as_int(q0.w);
        if (q1.x > V1) {                            // strict: q0 wins ties
            if (q1.z > V1) { V2 = q1.z; I2 = __float_as_int(q1.w); }
            else           { V2 = V1;   I2 = I1; }
            V1 = q1.x; I1 = __float_as_int(q1.y);
        } else if (q1.x > V2) {
            V2 = q1.x; I2 = __float_as_int(q1.y);
        }
        float d   = expf(V2 - V1);                  // softmax denom cancels
        float inv = 1.0f / (1.0f + d);
        res[tid] = make_float4(inv, __int_as_float(I1), d * inv, __int_as_float(I2));
    }
    __syncthreads();

    // ---- composed coalesced store: 32 tokens x 64 experts ----
    float4* outb = (float4*)out + (size_t)blockIdx.x * (TPB * E_DIM / 4);
    #pragma unroll
    for (int pp = 0; pp < 2; ++pp) {
        int p = tid + pp * 256;                     // 0..511
        int t = p >> 4, cc = p & 15;
        float4 rr = res[t];
        int ri1 = __float_as_int(rr.y), ri2 = __float_as_int(rr.w);
        int e = cc * 4;
        float4 o;
        o.x = (e + 0 == ri1) ? rr.x : (e + 0 == ri2) ? rr.z : 0.0f;
        o.y = (e + 1 == ri1) ? rr.x : (e + 1 == ri2) ? rr.z : 0.0f;
        o.z = (e + 2 == ri1) ? rr.x : (e + 2 == ri2) ? rr.z : 0.0f;
        o.w = (e + 3 == ri1) ? rr.x : (e + 3 == ri2) ? rr.z : 0.0f;
        outb[p] = o;
    }
}

extern "C" void kernel_launch(void* const* d_in, const int* in_sizes, int n_in,
                              void* d_out, int out_size, void* d_ws, size_t ws_size,
                              hipStream_t stream) {
    const float* x     = (const float*)d_in[0];
    const float* se    = (const float*)d_in[1];
    const float* W     = (const float*)d_in[2];
    const float* noise = (const float*)d_in[3];
    const int*   sidx  = (const int*)d_in[4];
    float* out = (float*)d_out;

    unsigned short* Wp   = (unsigned short*)d_ws;                 // 786432 B
    float*          tail = (float*)((char*)d_ws + WP_TOTAL);      // 256 B

    hipLaunchKernelGGL(prep_kernel, dim3(65), dim3(256), 0, stream, W, se, sidx, Wp, tail);
    hipLaunchKernelGGL(router_kernel, dim3(NBLOCKS), dim3(256), 0, stream,
                       x, (const unsigned char*)Wp, tail, noise, out);
}

// Round 12
// 222.744 us; speedup vs baseline: 1.3483x; 1.3483x over previous
//
#include <hip/hip_runtime.h>
#include <hip/hip_bf16.h>
#include <math.h>
#include <stdint.h>

// ScaleAdaptiveRouter on MI355X (gfx950) — Round 12
// T=16384, H=2048, E=64, K=2112, top-2.
//
// Plateau mechanism (R6..R11): compiler destroys register pipelines
// (spill/sink: R5,R8,R10,R11) and __syncthreads emits vmcnt(0) which drains
// glds prefetches of any depth (R10) -> every structure degenerates to a
// 1-deep pipeline paying full loaded latency per step (~95us).
// R12: glds multi-buffer (4 slots, depth-3) for BOTH A and B, with raw
//   "s_waitcnt vmcnt(8); s_barrier"  (inline asm) per step -- waits only for
// the oldest in-flight glds set; 2 newer sets stay in flight across the
// barrier (the hipBLASLt pattern the compiler can't express itself).
// A staged in fragment order w/ XOR-granule swizzle folded into the global
// source address (glds dst is lane-ordered, m104). bf16x3 6-term MFMA
// (R6-verified numerics); 32-expert/wave split; verified epilogue.

#define H_DIM 2048
#define K_TOTAL 2112
#define E_DIM 64
#define SE_DIM 64
#define NSTEP 64                        // K32 steps over H
#define TPB 32                          // tokens per block
#define NBLOCKS (16384 / TPB)           // 512 -> 2 blocks/CU
#define STEP_BYTES (12 * 1024)          // 12 B-records of 1 KB per step
#define WP_TOTAL (NSTEP * STEP_BYTES)   // 786432 B
#define MINS(v) ((v) < NSTEP ? (v) : (NSTEP - 1))

typedef float  f32x4 __attribute__((ext_vector_type(4)));
typedef short  s16x8 __attribute__((ext_vector_type(8)));
typedef unsigned int u32x4 __attribute__((ext_vector_type(4)));

typedef uint32_t __attribute__((address_space(1))) gu32_t;
typedef uint32_t __attribute__((address_space(3))) lu32_t;
__device__ __forceinline__ void gload_lds16(const void* g, void* l) {
    __builtin_amdgcn_global_load_lds((const gu32_t*)g, (lu32_t*)l, 16, 0, 0);
}

__device__ __forceinline__ unsigned short bf16_rne(float f) {
    uint32_t u = __float_as_uint(f);
    return (unsigned short)((u + 0x7FFFu + ((u >> 16) & 1u)) >> 16);
}
__device__ __forceinline__ float bf16_f32(unsigned short h) {
    return __uint_as_float(((uint32_t)h) << 16);
}
__device__ __forceinline__ uint32_t bits_of_bf2(__hip_bfloat162 h) {
    uint32_t u; __builtin_memcpy(&u, &h, 4); return u;
}

// ---- prep: split W into 3 bf16 planes laid out as MFMA B-fragments ----
// B-frag (16x16x32): lane l -> n = l&15, k = (l>>4)*8 + j. Record (s,nt,p):
// 64 lanes x 8 bf16 = 1 KB; record index = s*12 + nt*3 + p.  [R6-verified]
__global__ void prep_kernel(const float* __restrict__ W,
                            const float* __restrict__ se,
                            const int* __restrict__ sidx,
                            unsigned short* __restrict__ Wp,
                            float* __restrict__ tail) {
    if (blockIdx.x == 64) {
        int e = threadIdx.x;
        if (e < 64) {
            const float* emb = se + (*sidx) * SE_DIM;
            float t = 0.f;
            for (int j = 0; j < SE_DIM; ++j)
                t = fmaf(emb[j], W[(size_t)e * K_TOTAL + H_DIM + j], t);
            tail[e] = t;
        }
        return;
    }
    int item = blockIdx.x * 256 + threadIdx.x;   // (s, nt, lane)
    int lane = item & 63;
    int nt   = (item >> 6) & 3;
    int s    = item >> 8;
    int e     = nt * 16 + (lane & 15);
    int kbase = s * 32 + (lane >> 4) * 8;
    const float* wr = W + (size_t)e * K_TOTAL + kbase;
    unsigned short p0[8], p1[8], p2[8];
    #pragma unroll
    for (int j = 0; j < 8; ++j) {
        float v = wr[j];
        unsigned short a0 = bf16_rne(v);
        float r1 = v - bf16_f32(a0);
        unsigned short a1 = bf16_rne(r1);
        float r2 = r1 - bf16_f32(a1);
        p0[j] = a0; p1[j] = a1; p2[j] = bf16_rne(r2);
    }
    size_t rec = (size_t)s * 12 + nt * 3;
    unsigned short* d0 = Wp + (rec + 0) * 512 + lane * 8;
    unsigned short* d1 = Wp + (rec + 1) * 512 + lane * 8;
    unsigned short* d2 = Wp + (rec + 2) * 512 + lane * 8;
    #pragma unroll
    for (int j = 0; j < 8; ++j) { d0[j] = p0[j]; d1[j] = p1[j]; d2[j] = p2[j]; }
}

// split 8 consecutive-k floats into 3 bf16 A-fragment planes (packed pairs)
__device__ __forceinline__ void split3(const float4 fa, const float4 fb,
                                       s16x8& P0, s16x8& P1, s16x8& P2) {
    float f[8] = {fa.x, fa.y, fa.z, fa.w, fb.x, fb.y, fb.z, fb.w};
    uint32_t d0[4], d1[4], d2[4];
    #pragma unroll
    for (int p = 0; p < 4; ++p) {
        float v0 = f[2 * p], v1 = f[2 * p + 1];
        uint32_t u0 = bits_of_bf2(__float22bfloat162_rn(make_float2(v0, v1)));
        float r0 = v0 - __uint_as_float(u0 << 16);
        float r1 = v1 - __uint_as_float(u0 & 0xffff0000u);
        uint32_t u1 = bits_of_bf2(__float22bfloat162_rn(make_float2(r0, r1)));
        float s0 = r0 - __uint_as_float(u1 << 16);
        float s1 = r1 - __uint_as_float(u1 & 0xffff0000u);
        uint32_t u2 = bits_of_bf2(__float22bfloat162_rn(make_float2(s0, s1)));
        d0[p] = u0; d1[p] = u1; d2[p] = u2;
    }
    u32x4 q0 = {d0[0], d0[1], d0[2], d0[3]};
    u32x4 q1 = {d1[0], d1[1], d1[2], d1[3]};
    u32x4 q2 = {d2[0], d2[1], d2[2], d2[3]};
    __builtin_memcpy(&P0, &q0, 16);
    __builtin_memcpy(&P1, &q1, 16);
    __builtin_memcpy(&P2, &q2, 16);
}

__launch_bounds__(256, 2)
__global__ void router_kernel(const float* __restrict__ x,
                              const unsigned char* __restrict__ Wp,
                              const float* __restrict__ tail_g,
                              const float* __restrict__ noise,
                              float* __restrict__ out) {
    __shared__ __align__(16) unsigned char As[4][4096];     // 16 KB A slots
    __shared__ __align__(16) unsigned char Bs[4][STEP_BYTES]; // 48 KB B slots
    __shared__ float4 cand2[2][TPB];                        // 1 KB
    __shared__ float4 res[TPB];                             // 0.5 KB

    const int tid  = threadIdx.x;
    const int lane = tid & 63;
    const int wave = __builtin_amdgcn_readfirstlane(tid >> 6);
    const int mt   = wave >> 1;         // m-tile 0/1 (16 tokens each)
    const int g    = wave & 1;          // expert group: experts g*32 .. g*32+31
    const int tok0 = blockIdx.x * TPB;
    const int row  = lane & 15;         // token within m-tile
    const int quad = lane >> 4;         // k-quad
    const int c    = row;               // expert col within 16-slice

    // ---- staging decomposition (per thread, one A-glds + three B-glds/step) ----
    // A slot layout: [token][8 granules, pos p holds source chunk p^(tok&7)]
    const int stok = tid >> 3;                       // 0..31
    const int spos = tid & 7;                        // granule position
    const int schk = spos ^ (stok & 7);              // source chunk (swizzle)
    const float* asrc = x + (size_t)(tok0 + stok) * H_DIM + schk * 4;

    // A fragment read offsets (compute side): token mt*16+row, chunks 2q,2q+1
    const int abase = (mt * 16 + row) * 128;
    const int aoff0 = abase + (((quad * 2)     ^ (row & 7)) << 4);
    const int aoff1 = abase + (((quad * 2 + 1) ^ (row & 7)) << 4);

    f32x4 acc0 = {0.f, 0.f, 0.f, 0.f}, acc1 = acc0;

    // issue one full glds set (A 4KB + B 12KB) for step s into slot d
    #define ISSUE_SET(s_, d_) do {                                          \
        const unsigned char* _bsrc = Wp + (size_t)(s_) * STEP_BYTES;        \
        gload_lds16(asrc + (size_t)(s_) * 32, &As[d_][tid * 16]);           \
        gload_lds16(_bsrc + (size_t)tid * 16,          &Bs[d_][tid * 16]);          \
        gload_lds16(_bsrc + (size_t)(tid + 256) * 16,  &Bs[d_][(tid + 256) * 16]);  \
        gload_lds16(_bsrc + (size_t)(tid + 512) * 16,  &Bs[d_][(tid + 512) * 16]);  \
    } while (0)

    // ---- prologue: fill 3 sets (12 glds/thread outstanding) ----
    ISSUE_SET(0, 0);
    ISSUE_SET(1, 1);
    ISSUE_SET(2, 2);

    // ---- K loop: raw vmcnt(8)+barrier -> only the oldest set is drained;
    //      two newer sets stay in flight across the barrier ----
    for (int s = 0; s < NSTEP; ++s) {
        // wait: 12 outstanding -> 8 (oldest 4 = set s landed; in-order retire)
        asm volatile("s_waitcnt vmcnt(8)\n\ts_barrier" ::: "memory");

        const int slot = s & 3;
        const float4* ab = (const float4*)&As[slot][0];
        float4 a0 = *(const float4*)((const unsigned char*)ab + aoff0);
        float4 a1 = *(const float4*)((const unsigned char*)ab + aoff1);
        s16x8 A0, A1, A2;
        split3(a0, a1, A0, A1, A2);

        const unsigned char* base = &Bs[slot][g * 6144 + lane * 16];
        #pragma unroll
        for (int nt = 0; nt < 2; ++nt) {
            s16x8 B0 = *(const s16x8*)(base + (nt * 3 + 0) * 1024);
            s16x8 B1 = *(const s16x8*)(base + (nt * 3 + 1) * 1024);
            s16x8 B2 = *(const s16x8*)(base + (nt * 3 + 2) * 1024);
            f32x4 a = nt ? acc1 : acc0;
            a = __builtin_amdgcn_mfma_f32_16x16x32_bf16(A0, B0, a, 0, 0, 0);
            a = __builtin_amdgcn_mfma_f32_16x16x32_bf16(A0, B1, a, 0, 0, 0);
            a = __builtin_amdgcn_mfma_f32_16x16x32_bf16(A1, B0, a, 0, 0, 0);
            a = __builtin_amdgcn_mfma_f32_16x16x32_bf16(A0, B2, a, 0, 0, 0);
            a = __builtin_amdgcn_mfma_f32_16x16x32_bf16(A1, B1, a, 0, 0, 0);
            a = __builtin_amdgcn_mfma_f32_16x16x32_bf16(A2, B0, a, 0, 0, 0);
            if (nt) acc1 = a; else acc0 = a;
        }

        // issue set s+3 into slot (s+3)&3 (last read at step s-1 -> safe).
        // Past the end: clamped source, never-read slot -> keeps vmcnt
        // accounting uniform (always 4 issued per step).
        ISSUE_SET(MINS(s + 3), (s + 3) & 3);
    }
    #undef ISSUE_SET

    // ---- epilogue: tail + noise, top-2 over this wave's 32 experts ----
    // C/D: col = lane&15 -> expert g*32 + nt*16 + c; row = quad*4 + r -> token
    float tl0 = tail_g[g * 32 + c], tl1 = tail_g[g * 32 + 16 + c];
    #pragma unroll
    for (int r = 0; r < 4; ++r) {
        const int tl = mt * 16 + quad * 4 + r;              // block-local token
        const float* nz = noise + (size_t)(tok0 + tl) * E_DIM + g * 32;
        float v0 = acc0[r] + tl0 + 0.1f * nz[c];
        float v1 = acc1[r] + tl1 + 0.1f * nz[16 + c];
        // per-lane top-2 (v0's index < v1's index -> ties keep v0)
        float V1, V2; int I1, I2;
        if (v1 > v0) { V1 = v1; I1 = g * 32 + 16 + c; V2 = v0; I2 = g * 32 + c; }
        else         { V1 = v0; I1 = g * 32 + c;      V2 = v1; I2 = g * 32 + 16 + c; }
        // butterfly over the 16 lanes of this quad group
        #pragma unroll
        for (int m = 8; m; m >>= 1) {
            float o1 = __shfl_xor(V1, m, 64); int oi1 = __shfl_xor(I1, m, 64);
            float o2 = __shfl_xor(V2, m, 64); int oi2 = __shfl_xor(I2, m, 64);
            if (o1 > V1 || (o1 == V1 && oi1 < I1)) {
                float nv2; int ni2;
                if (V1 > o2 || (V1 == o2 && I1 < oi2)) { nv2 = V1; ni2 = I1; }
                else                                   { nv2 = o2; ni2 = oi2; }
                V1 = o1; I1 = oi1; V2 = nv2; I2 = ni2;
            } else {
                if (o1 > V2 || (o1 == V2 && oi1 < I2)) { V2 = o1; I2 = oi1; }
            }
        }
        if (c == r)
            cand2[g][tl] = make_float4(V1, __int_as_float(I1), V2, __int_as_float(I2));
    }
    __syncthreads();

    // ---- merge the two 32-expert groups per token (disjoint ranges: ties exact) ----
    if (tid < TPB) {
        float4 q0 = cand2[0][tid];                  // experts 0..31 (lower idx)
        float4 q1 = cand2[1][tid];                  // experts 32..63
        float V1 = q0.x, V2 = q0.z;
        int   I1 = __float_as_int(q0.y), I2 = __float_as_int(q0.w);
        if (q1.x > V1) {                            // strict: q0 wins ties
            if (q1.z > V1) { V2 = q1.z; I2 = __float_as_int(q1.w); }
            else           { V2 = V1;   I2 = I1; }
            V1 = q1.x; I1 = __float_as_int(q1.y);
        } else if (q1.x > V2) {
            V2 = q1.x; I2 = __float_as_int(q1.y);
        }
        float d   = expf(V2 - V1);                  // softmax denom cancels
        float inv = 1.0f / (1.0f + d);
        res[tid] = make_float4(inv, __int_as_float(I1), d * inv, __int_as_float(I2));
    }
    __syncthreads();

    // ---- composed coalesced store: 32 tokens x 64 experts ----
    float4* outb = (float4*)out + (size_t)blockIdx.x * (TPB * E_DIM / 4);
    #pragma unroll
    for (int pp = 0; pp < 2; ++pp) {
        int p = tid + pp * 256;                     // 0..511
        int t = p >> 4, cc = p & 15;
        float4 rr = res[t];
        int ri1 = __float_as_int(rr.y), ri2 = __float_as_int(rr.w);
        int e = cc * 4;
        float4 o;
        o.x = (e + 0 == ri1) ? rr.x : (e + 0 == ri2) ? rr.z : 0.0f;
        o.y = (e + 1 == ri1) ? rr.x : (e + 1 == ri2) ? rr.z : 0.0f;
        o.z = (e + 2 == ri1) ? rr.x : (e + 2 == ri2) ? rr.z : 0.0f;
        o.w = (e + 3 == ri1) ? rr.x : (e + 3 == ri2) ? rr.z : 0.0f;
        outb[p] = o;
    }
}

extern "C" void kernel_launch(void* const* d_in, const int* in_sizes, int n_in,
                              void* d_out, int out_size, void* d_ws, size_t ws_size,
                              hipStream_t stream) {
    const float* x     = (const float*)d_in[0];
    const float* se    = (const float*)d_in[1];
    const float* W     = (const float*)d_in[2];
    const float* noise = (const float*)d_in[3];
    const int*   sidx  = (const int*)d_in[4];
    float* out = (float*)d_out;

    unsigned short* Wp   = (unsigned short*)d_ws;                 // 786432 B
    float*          tail = (float*)((char*)d_ws + WP_TOTAL);      // 256 B

    hipLaunchKernelGGL(prep_kernel, dim3(65), dim3(256), 0, stream, W, se, sidx, Wp, tail);
    hipLaunchKernelGGL(router_kernel, dim3(NBLOCKS), dim3(256), 0, stream,
                       x, (const unsigned char*)Wp, tail, noise, out);
}